// Round 4
// baseline (697.033 us; speedup 1.0000x reference)
//
#include <hip/hip_runtime.h>

// ---------------------------------------------------------------------------
// Talking-heads attention, fused. B=2, N=M=2048, D=1024, H=16, dh=64.
// R8: R7's race-free 2-barrier structure + the 32 spare VGPRs spent on load
// pipelining: pass2 carries a K-tile prefetch across iterations (issued right
// after barrier A -> hidden under talk+LN+PV, drained at B), denom runs a
// 2-deep software pipeline (no barriers there). LDS layout, barrier schedule,
// epilogue: unchanged from R7.
// ---------------------------------------------------------------------------

typedef __attribute__((ext_vector_type(8))) short short8;
typedef __attribute__((ext_vector_type(4))) short short4v;
typedef __attribute__((ext_vector_type(4))) float float4v;
typedef unsigned short u16;

#define MFMA16(a, b, c) __builtin_amdgcn_mfma_f32_16x16x32_bf16((a), (b), (c), 0, 0, 0)
// K=16 talk MFMA: A,B are 4 bf16 (short4v). A[i=l15][k=lq*4+t], B[k][j=l15].
#define MFMA16K16(a, b, c) __builtin_amdgcn_mfma_f32_16x16x16bf16_1k((a), (b), (c), 0, 0, 0)

__device__ inline u16 f2bf(float f) {  // RNE f32->bf16 (inputs finite)
  unsigned u = __float_as_uint(f);
  u += 0x7FFFu + ((u >> 16) & 1u);
  return (u16)(u >> 16);
}
__device__ inline float bf2f(u16 u) {
  return __uint_as_float(((unsigned)u) << 16);
}
__device__ inline float fexp2(float x) { return __builtin_amdgcn_exp2f(x); }

// ---------------------------- cast kernel ----------------------------------
__global__ __launch_bounds__(256) void cast_bf16(const float* __restrict__ in,
                                                 u16* __restrict__ out, int n) {
  int i = (blockIdx.x * 256 + threadIdx.x) * 8;
  if (i + 8 > n) return;
  float4v f0 = *(const float4v*)(in + i);
  float4v f1 = *(const float4v*)(in + i + 4);
  short8 o;
  o[0] = (short)f2bf(f0[0]); o[1] = (short)f2bf(f0[1]);
  o[2] = (short)f2bf(f0[2]); o[3] = (short)f2bf(f0[3]);
  o[4] = (short)f2bf(f1[0]); o[5] = (short)f2bf(f1[1]);
  o[6] = (short)f2bf(f1[2]); o[7] = (short)f2bf(f1[3]);
  *(short8*)(out + i) = o;
}

// ------------------------ projection GEMM ----------------------------------
template <int MODE>
__global__ __launch_bounds__(256, 4) void gemm_bt(const u16* __restrict__ A,
                                                  const u16* __restrict__ W,
                                                  u16* __restrict__ out0,
                                                  u16* __restrict__ out1) {
  __shared__ u16 As[64][40];
  __shared__ u16 Ws[64][40];
  const int t = threadIdx.x;
  const int wave = t >> 6, l = t & 63, l15 = l & 15, lq = l >> 4;
  const int r0 = blockIdx.x * 64, c0 = blockIdx.y * 64;
  const int srow = t >> 2, sch = t & 3;
  const u16* ag = A + (r0 + srow) * 1024 + sch * 8;
  const u16* wg = W + (c0 + srow) * 1024 + sch * 8;

  float4v acc[4];
#pragma unroll
  for (int i = 0; i < 4; ++i) acc[i] = (float4v){0.f, 0.f, 0.f, 0.f};

  short8 av = *(const short8*)ag;
  short8 wv = *(const short8*)wg;
  for (int kt = 0; kt < 32; ++kt) {
    __syncthreads();
    *(short8*)&As[srow][sch * 8] = av;
    *(short8*)&Ws[srow][sch * 8] = wv;
    __syncthreads();
    if (kt < 31) {
      av = *(const short8*)(ag + (kt + 1) * 32);
      wv = *(const short8*)(wg + (kt + 1) * 32);
    }
    short8 af = *(const short8*)&As[wave * 16 + l15][lq * 8];
#pragma unroll
    for (int fn = 0; fn < 4; ++fn) {
      short8 bf = *(const short8*)&Ws[fn * 16 + l15][lq * 8];
      acc[fn] = MFMA16(af, bf, acc[fn]);
    }
  }
#pragma unroll
  for (int fn = 0; fn < 4; ++fn) {
#pragma unroll
    for (int r = 0; r < 4; ++r) {
      int row = r0 + wave * 16 + lq * 4 + r;
      int col = c0 + fn * 16 + l15;
      int b = row >> 11, n = row & 2047;
      float v = acc[fn][r];
      if (MODE == 0) {
        // dh^-0.5 * log2(e): softmax done in base 2 (v_exp_f32 is 2^x)
        v *= 0.125f * 1.44269504088896f;
        int h = col >> 6, d = col & 63;
        out0[(((b * 16 + h) * 2048 + n) << 6) + d] = f2bf(v);
      } else {
        if (col < 1024) {
          int h = col >> 6, d = col & 63;
          out0[(((b * 16 + h) * 2048 + n) << 6) + d] = f2bf(v);
        } else {
          int cc = col - 1024;
          int h = cc >> 6, d = cc & 63;
          out1[(((b * 16 + h) * 2048 + n) << 6) + d] = f2bf(v);
        }
      }
    }
  }
}

// --------------------------- V transpose + column sums ---------------------
// Also accumulates vsum[b][h][jh][d] = sum_{j in half jh} V[b,h,j,d] (f32),
// used to fold LN beta into the attention epilogue.
__global__ __launch_bounds__(256) void transpose_v(const u16* __restrict__ vh,
                                                   u16* __restrict__ vt,
                                                   float* __restrict__ vsum) {
  __shared__ u16 tile[64][72];
  const int t = threadIdx.x;
  const int j0 = blockIdx.x * 64, h = blockIdx.y, b = blockIdx.z;
  const u16* src = vh + (((b * 16 + h) * 2048 + j0) << 6);
  int row = t >> 2, c = t & 3;
  short8 v0 = *(const short8*)(src + row * 64 + c * 8);
  short8 v1 = *(const short8*)(src + row * 64 + (c + 4) * 8);
  *(short8*)&tile[row][c * 8] = v0;
  *(short8*)&tile[row][(c + 4) * 8] = v1;
  __syncthreads();
  int d = t >> 2, jc = t & 3;
  short8 o0, o1;
#pragma unroll
  for (int jj = 0; jj < 8; ++jj) o0[jj] = (short)tile[jc * 16 + jj][d];
#pragma unroll
  for (int jj = 0; jj < 8; ++jj) o1[jj] = (short)tile[jc * 16 + 8 + jj][d];
  u16* dst = vt + ((b * 16 + h) * 64 + d) * 2048 + j0 + jc * 16;
  *(short8*)dst = o0;
  *(short8*)(dst + 8) = o1;
  // column-sum contribution (16 j's per thread)
  float s = 0.f;
#pragma unroll
  for (int jj = 0; jj < 8; ++jj) s += bf2f((u16)o0[jj]) + bf2f((u16)o1[jj]);
  int jh = blockIdx.x >> 4;  // j0 / 1024
  atomicAdd(vsum + ((b * 16 + h) * 2 + jh) * 64 + d, s);
}

// ----------------------- softmax denominators ------------------------------
// grid (itile=128, jhalf=2, b=2) = 512 blocks, 16 waves, NO LDS, no barriers.
// 2-deep software pipeline (named A/B register sets, unroll-by-2): K loads
// issued a full iteration before use -> latency hidden under MFMA+exp.
__global__ __launch_bounds__(1024, 8) void attn_denom(
    const u16* __restrict__ qh, const u16* __restrict__ kh,
    float* __restrict__ lsum) {
  const int tid = threadIdx.x;
  const int wv = tid >> 6;  // wave id == head
  const int l = tid & 63, l15 = l & 15, lq = l >> 4;
  const int i0 = blockIdx.x * 16;
  const int jh = blockIdx.y;
  const int b = blockIdx.z;
  const int bh = b * 16 + wv;

  const u16* qbase = qh + ((bh * 2048 + i0) << 6);
  short8 qf0 = *(const short8*)(qbase + l15 * 64 + lq * 8);
  short8 qf1 = *(const short8*)(qbase + l15 * 64 + 32 + lq * 8);
  // lane base into K; fragment offsets: +32 (k-half), +1024 (rows +16),
  // +1056; tile stride = 32 rows * 64 = 2048 elems.
  const u16* kl = kh + ((bh * 2048 + jh * 1024) << 6) + l15 * 64 + lq * 8;

  float ps0 = 0.f, ps1 = 0.f, ps2 = 0.f, ps3 = 0.f;
  short8 a0 = *(const short8*)(kl);
  short8 a1 = *(const short8*)(kl + 32);
  short8 a2 = *(const short8*)(kl + 1024);
  short8 a3 = *(const short8*)(kl + 1056);
  short8 b0 = *(const short8*)(kl + 2048);
  short8 b1 = *(const short8*)(kl + 2048 + 32);
  short8 b2 = *(const short8*)(kl + 2048 + 1024);
  short8 b3 = *(const short8*)(kl + 2048 + 1056);
#pragma unroll 1
  for (int jt = 0; jt < 32; jt += 2) {
    {  // tile jt (A set), refill A for jt+2
      float4v s0 = {0.f, 0.f, 0.f, 0.f}, s1 = {0.f, 0.f, 0.f, 0.f};
      s0 = MFMA16(qf0, a0, s0);
      s0 = MFMA16(qf1, a1, s0);
      s1 = MFMA16(qf0, a2, s1);
      s1 = MFMA16(qf1, a3, s1);
      if (jt + 2 < 32) {
        const u16* kp = kl + (jt + 2) * 2048;
        a0 = *(const short8*)(kp);
        a1 = *(const short8*)(kp + 32);
        a2 = *(const short8*)(kp + 1024);
        a3 = *(const short8*)(kp + 1056);
      }
      ps0 += fexp2(s0[0]) + fexp2(s1[0]);
      ps1 += fexp2(s0[1]) + fexp2(s1[1]);
      ps2 += fexp2(s0[2]) + fexp2(s1[2]);
      ps3 += fexp2(s0[3]) + fexp2(s1[3]);
    }
    {  // tile jt+1 (B set), refill B for jt+3
      float4v s0 = {0.f, 0.f, 0.f, 0.f}, s1 = {0.f, 0.f, 0.f, 0.f};
      s0 = MFMA16(qf0, b0, s0);
      s0 = MFMA16(qf1, b1, s0);
      s1 = MFMA16(qf0, b2, s1);
      s1 = MFMA16(qf1, b3, s1);
      if (jt + 3 < 32) {
        const u16* kp = kl + (jt + 3) * 2048;
        b0 = *(const short8*)(kp);
        b1 = *(const short8*)(kp + 32);
        b2 = *(const short8*)(kp + 1024);
        b3 = *(const short8*)(kp + 1056);
      }
      ps0 += fexp2(s0[0]) + fexp2(s1[0]);
      ps1 += fexp2(s0[1]) + fexp2(s1[1]);
      ps2 += fexp2(s0[2]) + fexp2(s1[2]);
      ps3 += fexp2(s0[3]) + fexp2(s1[3]);
    }
  }
#pragma unroll
  for (int d = 1; d < 16; d <<= 1) {
    ps0 += __shfl_xor(ps0, d);
    ps1 += __shfl_xor(ps1, d);
    ps2 += __shfl_xor(ps2, d);
    ps3 += __shfl_xor(ps3, d);
  }
  if (l15 == 0) {
    float* lp = lsum + bh * 2048 + i0 + lq * 4;
    atomicAdd(lp + 0, ps0);
    atomicAdd(lp + 1, ps1);
    atomicAdd(lp + 2, ps2);
    atomicAdd(lp + 3, ps3);
  }
}

// ------------------------- fused attention pass 2 --------------------------
// grid (itile=128, jhalf=2, b=2) = 512 blocks, 16 waves (wave == head).
// LDS 36.9 KB single-buffer, 2 barriers/iter (race-free, same as R7):
//   QK(jt)+P-write | A | [kn prefetch] talk(jt)->z regs, PV(jt-1) | B | Y-wr
// New in R8: K tile jt+1 prefetched into registers right after barrier A —
// in flight under talk+LN+PV, drained at B, consumed by next iter's QK.
__global__ __launch_bounds__(1024, 8) void attn_pass2(
    const u16* __restrict__ qh, const u16* __restrict__ kh,
    const u16* __restrict__ vt, const float* __restrict__ wtalk,
    const float* __restrict__ gamma, const float* __restrict__ beta,
    const float* __restrict__ lsum, const float* __restrict__ vsum,
    float* __restrict__ out) {
  __shared__ u16 P_lds[512 * 18];  // [e=i*32+jl][18]; cols 0..15 used
  __shared__ u16 Y_lds[256 * 36];  // [g*16+i][36];   cols 0..31 used

  const int tid = threadIdx.x;
  const int wv = tid >> 6;  // wave id == head
  const int l = tid & 63, l15 = l & 15, lq = l >> 4;
  const int i0 = blockIdx.x * 16;
  const int jh = blockIdx.y;
  const int b = blockIdx.z;
  const int bh = b * 16 + wv;

  // Wtalk A-fragment for K=16 MFMA: A[g=l15][h=lq*4+t]
  short4v wfrag;
#pragma unroll
  for (int t4 = 0; t4 < 4; ++t4)
    wfrag[t4] = (short)f2bf(wtalk[l15 * 16 + lq * 4 + t4]);

  const u16* qbase = qh + ((bh * 2048 + i0) << 6);
  short8 qf0 = *(const short8*)(qbase + l15 * 64 + lq * 8);
  short8 qf1 = *(const short8*)(qbase + l15 * 64 + 32 + lq * 8);
  // lane base into K; fragment offsets +32/+1024/+1056; tile stride 2048.
  const u16* klane = kh + ((bh * 2048 + jh * 1024) << 6) + l15 * 64 + lq * 8;
  const u16* vbase = vt + (bh * 64) * 2048 + jh * 1024;

  // bias: -log2(denominator), P = 2^(s + bc)
  float bc[4];
#pragma unroll
  for (int r = 0; r < 4; ++r)
    bc[r] = -__builtin_amdgcn_logf(lsum[bh * 2048 + i0 + lq * 4 + r]);

  float4v acc0 = {0.f, 0.f, 0.f, 0.f}, acc1 = acc0, acc2 = acc0, acc3 = acc0;
  short8 zf;  // pending Y(jt) values (bf16), stored after BARRIER_B

  // preload K tile 0
  short8 kc0 = *(const short8*)(klane);
  short8 kc1 = *(const short8*)(klane + 32);
  short8 kc2 = *(const short8*)(klane + 1024);
  short8 kc3 = *(const short8*)(klane + 1056);
  short8 kn0 = kc0, kn1 = kc1, kn2 = kc2, kn3 = kc3;

#pragma unroll 1
  for (int jt = 0; jt <= 32; ++jt) {
    if (jt < 32) {
      // QK for tile jt (prefetched kc), P-write
      float4v s0 = {0.f, 0.f, 0.f, 0.f}, s1 = {0.f, 0.f, 0.f, 0.f};
      s0 = MFMA16(qf0, kc0, s0);
      s0 = MFMA16(qf1, kc1, s0);
      s1 = MFMA16(qf0, kc2, s1);
      s1 = MFMA16(qf1, kc3, s1);
      // P = 2^(S - log2 l) -> bf16 -> P_lds[e][wv] (stride 18)
      int ebase = lq * 128 + l15;
#pragma unroll
      for (int r = 0; r < 4; ++r) {
        float p0 = fexp2(s0[r] + bc[r]);
        float p1 = fexp2(s1[r] + bc[r]);
        P_lds[(ebase + r * 32) * 18 + wv] = f2bf(p0);
        P_lds[(ebase + r * 32 + 16) * 18 + wv] = f2bf(p1);
      }
    }
    __syncthreads();  // A: P(jt) visible; Y(jt-1) writes (pre-A) visible
    if (jt + 1 < 32) {
      // K prefetch for tile jt+1: in flight during talk+LN+PV, drained at B
      const u16* kp = klane + (jt + 1) * 2048;
      kn0 = *(const short8*)(kp);
      kn1 = *(const short8*)(kp + 32);
      kn2 = *(const short8*)(kp + 1024);
      kn3 = *(const short8*)(kp + 1056);
    }
    if (jt < 32) {
      // talk (K=16): wave wv covers e in [wv*32, wv*32+32), i.e. i == wv
      float4v t0 = {0.f, 0.f, 0.f, 0.f}, t1 = {0.f, 0.f, 0.f, 0.f};
      {
        const u16* prow = &P_lds[(wv * 32 + l15) * 18 + (lq << 2)];
        union { int i2[2]; short4v s4; } u0, u1;
        u0.i2[0] = *(const int*)(prow);
        u0.i2[1] = *(const int*)(prow + 2);
        u1.i2[0] = *(const int*)(prow + 16 * 18);
        u1.i2[1] = *(const int*)(prow + 16 * 18 + 2);
        t0 = MFMA16K16(wfrag, u0.s4, t0);
        t1 = MFMA16K16(wfrag, u1.s4, t1);
      }
      // head-LN per (i,j) column: z kept in regs until after BARRIER_B
#pragma unroll
      for (int c2 = 0; c2 < 2; ++c2) {
        float4v tt = c2 ? t1 : t0;
        float sum = tt[0] + tt[1] + tt[2] + tt[3];
        sum += __shfl_xor(sum, 16);
        sum += __shfl_xor(sum, 32);
        float mu = sum * 0.0625f;
        float ss = tt[0] * tt[0] + tt[1] * tt[1] + tt[2] * tt[2] + tt[3] * tt[3];
        ss += __shfl_xor(ss, 16);
        ss += __shfl_xor(ss, 32);
        float var = ss * 0.0625f - mu * mu;
        float rs = rsqrtf(var + 1e-5f);
#pragma unroll
        for (int r = 0; r < 4; ++r)
          zf[c2 * 4 + r] = (short)f2bf((tt[r] - mu) * rs);
      }
    }
    if (jt >= 1) {
      // PV for tile jt-1 (Y written before A of this iter, barrier-safe)
      const u16* vp = vbase + (jt - 1) * 32 + lq * 8;
      short8 yf = *(const short8*)&Y_lds[(wv * 16 + l15) * 36 + lq * 8];
      short8 va = *(const short8*)(vp + l15 * 2048);
      short8 vb = *(const short8*)(vp + (16 + l15) * 2048);
      acc0 = MFMA16(yf, va, acc0);
      va = *(const short8*)(vp + (32 + l15) * 2048);
      acc1 = MFMA16(yf, vb, acc1);
      vb = *(const short8*)(vp + (48 + l15) * 2048);
      acc2 = MFMA16(yf, va, acc2);
      acc3 = MFMA16(yf, vb, acc3);
    }
    __syncthreads();  // B: all PV reads of Y(jt-1) complete; kn drained
    if (jt < 32) {
      // Y-write(jt): safe to overwrite now
#pragma unroll
      for (int c2 = 0; c2 < 2; ++c2)
#pragma unroll
        for (int r = 0; r < 4; ++r)
          Y_lds[((lq * 4 + r) * 16 + wv) * 36 + c2 * 16 + l15] =
              (u16)zf[c2 * 4 + r];
    }
    kc0 = kn0; kc1 = kn1; kc2 = kn2; kc3 = kn3;
  }
  // epilogue: out_partial = gamma[g]*acc + beta[g]*vsum_half (g == wv)
  const float gamw = gamma[wv], betw = beta[wv];
  const float* vs = vsum + ((b * 16 + wv) * 2 + jh) * 64;
  const float bv0 = betw * vs[l15];
  const float bv1 = betw * vs[16 + l15];
  const float bv2 = betw * vs[32 + l15];
  const float bv3 = betw * vs[48 + l15];
  float* ob = out + (b * 2048 + i0) * 1024 + wv * 64;
#pragma unroll
  for (int r = 0; r < 4; ++r) {
    float* orow = ob + (lq * 4 + r) * 1024;
    atomicAdd(orow + l15, gamw * acc0[r] + bv0);
    atomicAdd(orow + 16 + l15, gamw * acc1[r] + bv1);
    atomicAdd(orow + 32 + l15, gamw * acc2[r] + bv2);
    atomicAdd(orow + 48 + l15, gamw * acc3[r] + bv3);
  }
}

// ----------------------------- launcher ------------------------------------
extern "C" void kernel_launch(void* const* d_in, const int* in_sizes, int n_in,
                              void* d_out, int out_size, void* d_ws,
                              size_t ws_size, hipStream_t stream) {
  const float* x = (const float*)d_in[0];
  const float* ctx = (const float*)d_in[1];
  const float* Wq = (const float*)d_in[2];
  const float* Wkv = (const float*)d_in[3];
  const float* Wtalk = (const float*)d_in[4];
  const float* gam = (const float*)d_in[5];
  const float* bet = (const float*)d_in[6];
  float* out = (float*)d_out;

  u16* xb = (u16*)d_ws;            // 4  Mi elems
  u16* cb = xb + 4194304;          // 4  Mi
  u16* wqb = cb + 4194304;         // 1  Mi
  u16* wkvb = wqb + 1048576;       // 2  Mi
  u16* qhb = wkvb + 2097152;       // 4  Mi  [b][h][n][64]
  u16* khb = qhb + 4194304;        // 4  Mi  [b][h][j][64]
  u16* vhb = khb + 4194304;        // 4  Mi  [b][h][j][64]
  u16* vtb = vhb + 4194304;        // 4  Mi  [b][h][d][2048]
  float* lsum = (float*)(vtb + 4194304);  // 64 Ki f32  [b][h][i]
  float* vsum = lsum + 65536;             // 4 Ki f32   [b][h][jh][d]

  hipMemsetAsync(lsum, 0, 65536 * sizeof(float), stream);
  hipMemsetAsync(vsum, 0, 4096 * sizeof(float), stream);
  hipMemsetAsync(out, 0, 2 * 2048 * 1024 * sizeof(float), stream);

  cast_bf16<<<2048, 256, 0, stream>>>(x, xb, 4194304);
  cast_bf16<<<2048, 256, 0, stream>>>(ctx, cb, 4194304);
  cast_bf16<<<512, 256, 0, stream>>>(Wq, wqb, 1048576);
  cast_bf16<<<1024, 256, 0, stream>>>(Wkv, wkvb, 2097152);

  gemm_bt<0><<<dim3(64, 16), 256, 0, stream>>>(xb, wqb, qhb, nullptr);
  gemm_bt<1><<<dim3(64, 32), 256, 0, stream>>>(cb, wkvb, khb, vhb);

  transpose_v<<<dim3(32, 16, 2), 256, 0, stream>>>(vhb, vtb, vsum);

  attn_denom<<<dim3(128, 2, 2), 1024, 0, stream>>>(qhb, khb, lsum);
  attn_pass2<<<dim3(128, 2, 2), 1024, 0, stream>>>(qhb, khb, vtb, Wtalk, gam,
                                                   bet, lsum, vsum, out);
}

// Round 5
// 622.151 us; speedup vs baseline: 1.1204x; 1.1204x over previous
//
#include <hip/hip_runtime.h>

// ---------------------------------------------------------------------------
// Talking-heads attention. B=2, N=M=2048, D=1024, H=16, dh=64.
// R9: abandon the latency-bound fused loop (R4-R8 showed an invariant
// ~4.6us/iter serial chain independent of occupancy). Decompose into three
// throughput-shaped kernels with a materialized E=2^s intermediate (bf16),
// i-quartered to bound workspace (~93MB):
//   A qk_exp  : S=QK^T -> E=2^S (packed 8B stores) + row-sum atomics (lsum)
//   B talk_ln : in-place streaming E->Y: p=E/l, t=Wtalk.p (in-reg matvec),
//               LN over heads in-reg, y = z*gamma+beta  (no LDS/barriers)
//   C pv_gemm : out = Y.V^T, gemm_bt-template batched GEMM, f32 stores
// Prestage (casts, projection GEMMs, V transpose) unchanged from R4.
// ---------------------------------------------------------------------------

typedef __attribute__((ext_vector_type(8))) short short8;
typedef __attribute__((ext_vector_type(4))) short short4v;
typedef __attribute__((ext_vector_type(4))) float float4v;
typedef unsigned short u16;

#define MFMA16(a, b, c) __builtin_amdgcn_mfma_f32_16x16x32_bf16((a), (b), (c), 0, 0, 0)

__device__ inline u16 f2bf(float f) {  // RNE f32->bf16 (inputs finite)
  unsigned u = __float_as_uint(f);
  u += 0x7FFFu + ((u >> 16) & 1u);
  return (u16)(u >> 16);
}
__device__ inline float bf2f(u16 u) {
  return __uint_as_float(((unsigned)u) << 16);
}
__device__ inline float fexp2(float x) { return __builtin_amdgcn_exp2f(x); }

// ---------------------------- cast kernel ----------------------------------
__global__ __launch_bounds__(256) void cast_bf16(const float* __restrict__ in,
                                                 u16* __restrict__ out, int n) {
  int i = (blockIdx.x * 256 + threadIdx.x) * 8;
  if (i + 8 > n) return;
  float4v f0 = *(const float4v*)(in + i);
  float4v f1 = *(const float4v*)(in + i + 4);
  short8 o;
  o[0] = (short)f2bf(f0[0]); o[1] = (short)f2bf(f0[1]);
  o[2] = (short)f2bf(f0[2]); o[3] = (short)f2bf(f0[3]);
  o[4] = (short)f2bf(f1[0]); o[5] = (short)f2bf(f1[1]);
  o[6] = (short)f2bf(f1[2]); o[7] = (short)f2bf(f1[3]);
  *(short8*)(out + i) = o;
}

// ------------------------ projection GEMM ----------------------------------
template <int MODE>
__global__ __launch_bounds__(256, 4) void gemm_bt(const u16* __restrict__ A,
                                                  const u16* __restrict__ W,
                                                  u16* __restrict__ out0,
                                                  u16* __restrict__ out1) {
  __shared__ u16 As[64][40];
  __shared__ u16 Ws[64][40];
  const int t = threadIdx.x;
  const int wave = t >> 6, l = t & 63, l15 = l & 15, lq = l >> 4;
  const int r0 = blockIdx.x * 64, c0 = blockIdx.y * 64;
  const int srow = t >> 2, sch = t & 3;
  const u16* ag = A + (r0 + srow) * 1024 + sch * 8;
  const u16* wg = W + (c0 + srow) * 1024 + sch * 8;

  float4v acc[4];
#pragma unroll
  for (int i = 0; i < 4; ++i) acc[i] = (float4v){0.f, 0.f, 0.f, 0.f};

  short8 av = *(const short8*)ag;
  short8 wv = *(const short8*)wg;
  for (int kt = 0; kt < 32; ++kt) {
    __syncthreads();
    *(short8*)&As[srow][sch * 8] = av;
    *(short8*)&Ws[srow][sch * 8] = wv;
    __syncthreads();
    if (kt < 31) {
      av = *(const short8*)(ag + (kt + 1) * 32);
      wv = *(const short8*)(wg + (kt + 1) * 32);
    }
    short8 af = *(const short8*)&As[wave * 16 + l15][lq * 8];
#pragma unroll
    for (int fn = 0; fn < 4; ++fn) {
      short8 bf = *(const short8*)&Ws[fn * 16 + l15][lq * 8];
      acc[fn] = MFMA16(af, bf, acc[fn]);
    }
  }
#pragma unroll
  for (int fn = 0; fn < 4; ++fn) {
#pragma unroll
    for (int r = 0; r < 4; ++r) {
      int row = r0 + wave * 16 + lq * 4 + r;
      int col = c0 + fn * 16 + l15;
      int b = row >> 11, n = row & 2047;
      float v = acc[fn][r];
      if (MODE == 0) {
        // dh^-0.5 * log2(e): softmax done in base 2 (v_exp_f32 is 2^x)
        v *= 0.125f * 1.44269504088896f;
        int h = col >> 6, d = col & 63;
        out0[(((b * 16 + h) * 2048 + n) << 6) + d] = f2bf(v);
      } else {
        if (col < 1024) {
          int h = col >> 6, d = col & 63;
          out0[(((b * 16 + h) * 2048 + n) << 6) + d] = f2bf(v);
        } else {
          int cc = col - 1024;
          int h = cc >> 6, d = cc & 63;
          out1[(((b * 16 + h) * 2048 + n) << 6) + d] = f2bf(v);
        }
      }
    }
  }
}

// --------------------------- V transpose -----------------------------------
__global__ __launch_bounds__(256) void transpose_v(const u16* __restrict__ vh,
                                                   u16* __restrict__ vt) {
  __shared__ u16 tile[64][72];
  const int t = threadIdx.x;
  const int j0 = blockIdx.x * 64, h = blockIdx.y, b = blockIdx.z;
  const u16* src = vh + (((b * 16 + h) * 2048 + j0) << 6);
  int row = t >> 2, c = t & 3;
  short8 v0 = *(const short8*)(src + row * 64 + c * 8);
  short8 v1 = *(const short8*)(src + row * 64 + (c + 4) * 8);
  *(short8*)&tile[row][c * 8] = v0;
  *(short8*)&tile[row][(c + 4) * 8] = v1;
  __syncthreads();
  int d = t >> 2, jc = t & 3;
  short8 o0, o1;
#pragma unroll
  for (int jj = 0; jj < 8; ++jj) o0[jj] = (short)tile[jc * 16 + jj][d];
#pragma unroll
  for (int jj = 0; jj < 8; ++jj) o1[jj] = (short)tile[jc * 16 + 8 + jj][d];
  u16* dst = vt + ((b * 16 + h) * 64 + d) * 2048 + j0 + jc * 16;
  *(short8*)dst = o0;
  *(short8*)(dst + 8) = o1;
}

// ------------------------ A: QK^T -> E = 2^S -------------------------------
// grid (itile=8, jtile=32, bh=32) per i-quarter, 256 threads (4 waves).
// Operand-swapped MFMA (K as x-operand) puts j in-lane -> packed 8B stores.
// Row sums (over the bf16-ROUNDED E, matching what talk_ln reads) atomically
// accumulated into lsum[bh][i_global].
__global__ __launch_bounds__(256) void qk_exp(const u16* __restrict__ qh,
                                              const u16* __restrict__ kh,
                                              u16* __restrict__ E,
                                              float* __restrict__ lsum,
                                              int i_base) {
  const int t = threadIdx.x;
  const int w = t >> 6, l = t & 63, l15 = l & 15, lq = l >> 4;
  const int it = blockIdx.x;
  const int jt = blockIdx.y;
  const int bh = blockIdx.z;
  const int i0w = it * 64 + w * 16;  // quarter-local i of this wave's strip
  const int ig = i_base + i0w;       // global i
  const int j0 = jt * 64;

  const u16* qb = qh + (size_t)(bh * 2048 + ig + l15) * 64 + lq * 8;
  short8 qf0 = *(const short8*)qb;
  short8 qf1 = *(const short8*)(qb + 32);
  const u16* kb = kh + (size_t)(bh * 2048 + j0 + l15) * 64 + lq * 8;

  // s[fn][r]: x-row (K) = j0+fn*16+lq*4+r, y-row (Q) = i0w+l15
  float4v s[4];
#pragma unroll
  for (int fn = 0; fn < 4; ++fn) {
    short8 k0 = *(const short8*)(kb + fn * 16 * 64);
    short8 k1 = *(const short8*)(kb + fn * 16 * 64 + 32);
    float4v a = {0.f, 0.f, 0.f, 0.f};
    a = MFMA16(k0, qf0, a);
    a = MFMA16(k1, qf1, a);
    s[fn] = a;
  }

  u16* eb = E + ((size_t)(bh * 512 + i0w + l15)) * 2048 + j0 + lq * 4;
  float rs = 0.f;
#pragma unroll
  for (int fn = 0; fn < 4; ++fn) {
    short4v pk;
#pragma unroll
    for (int r = 0; r < 4; ++r) {
      u16 ev = f2bf(fexp2(s[fn][r]));
      pk[r] = (short)ev;
      rs += bf2f(ev);
    }
    *(short4v*)(eb + fn * 16) = pk;  // 4 consecutive j, 8B store
  }
  // reduce rs across lq groups (rows indexed by l15)
  rs += __shfl_xor(rs, 16);
  rs += __shfl_xor(rs, 32);
  if (l < 16) atomicAdd(lsum + (size_t)bh * 2048 + ig + (l - l15) + l15, rs);
}

// ------------------------ B: talk + head-LN (in place) ---------------------
// grid (jchunk=4, iq=512, b=2), 256 threads. Thread owns 2 consecutive j at
// one (b,i): reads 16 h-planes (u32 each, wave-coalesced), p=E*inv_l,
// t=Wtalk.p (256 FMA in-reg), LN over g in-reg, y=z*gamma+beta -> bf16,
// written over E. All-reads-before-all-writes per thread (true data dep).
__global__ __launch_bounds__(256) void talk_ln(u16* ey,
                                               const float* __restrict__ lsum,
                                               const float* __restrict__ wtalk,
                                               const float* __restrict__ gamma,
                                               const float* __restrict__ beta,
                                               int i_base) {
  __shared__ float wt[256];
  __shared__ float invl[16], ga[16], be[16];
  const int tid = threadIdx.x;
  const int jc = blockIdx.x, iq = blockIdx.y, b = blockIdx.z;
  const int ig = i_base + iq;
  wt[tid] = wtalk[tid];
  if (tid < 16) {
    invl[tid] = 1.f / lsum[(size_t)(b * 16 + tid) * 2048 + ig];
    ga[tid] = gamma[tid];
    be[tid] = beta[tid];
  }
  __syncthreads();

  const int j = jc * 512 + tid * 2;
  const size_t base = ((size_t)(b * 16) * 512 + iq) * 2048 + j;
  const size_t hstride = (size_t)512 * 2048;

  float p0[16], p1[16];
#pragma unroll
  for (int h = 0; h < 16; ++h) {
    unsigned u = *(const unsigned*)(ey + base + h * hstride);
    float il = invl[h];
    p0[h] = bf2f((u16)(u & 0xffffu)) * il;
    p1[h] = bf2f((u16)(u >> 16)) * il;
  }
  float t0[16], t1[16];
#pragma unroll
  for (int g = 0; g < 16; ++g) { t0[g] = 0.f; t1[g] = 0.f; }
#pragma unroll
  for (int h = 0; h < 16; ++h) {
#pragma unroll
    for (int g = 0; g < 16; ++g) {
      float wv = wt[g * 16 + h];
      t0[g] += wv * p0[h];
      t1[g] += wv * p1[h];
    }
  }
  float mu0 = 0.f, mu1 = 0.f, ss0 = 0.f, ss1 = 0.f;
#pragma unroll
  for (int g = 0; g < 16; ++g) {
    mu0 += t0[g]; ss0 += t0[g] * t0[g];
    mu1 += t1[g]; ss1 += t1[g] * t1[g];
  }
  mu0 *= 0.0625f; mu1 *= 0.0625f;
  float rv0 = rsqrtf(ss0 * 0.0625f - mu0 * mu0 + 1e-5f);
  float rv1 = rsqrtf(ss1 * 0.0625f - mu1 * mu1 + 1e-5f);
#pragma unroll
  for (int g = 0; g < 16; ++g) {
    float y0 = (t0[g] - mu0) * rv0 * ga[g] + be[g];
    float y1 = (t1[g] - mu1) * rv1 * ga[g] + be[g];
    unsigned o = (unsigned)f2bf(y0) | ((unsigned)f2bf(y1) << 16);
    *(unsigned*)(ey + base + g * hstride) = o;
  }
}

// ------------------------ C: PV GEMM (out = Y . V^T) -----------------------
// grid (itile=8, bg=32) per quarter. gemm_bt template: A=Y (K=j contiguous),
// W=V^T (K=j contiguous), K=2048, 64 k-steps, f32 direct stores.
__global__ __launch_bounds__(256, 4) void pv_gemm(const u16* __restrict__ Y,
                                                  const u16* __restrict__ VT,
                                                  float* __restrict__ out,
                                                  int i_base) {
  __shared__ u16 As[64][40];
  __shared__ u16 Ws[64][40];
  const int t = threadIdx.x;
  const int wave = t >> 6, l = t & 63, l15 = l & 15, lq = l >> 4;
  const int r0 = blockIdx.x * 64;
  const int bg = blockIdx.y;
  const int srow = t >> 2, sch = t & 3;
  const u16* ag = Y + ((size_t)bg * 512 + r0 + srow) * 2048 + sch * 8;
  const u16* wg = VT + ((size_t)bg * 64 + srow) * 2048 + sch * 8;

  float4v acc[4];
#pragma unroll
  for (int i = 0; i < 4; ++i) acc[i] = (float4v){0.f, 0.f, 0.f, 0.f};

  short8 av = *(const short8*)ag;
  short8 wv = *(const short8*)wg;
  for (int kt = 0; kt < 64; ++kt) {
    __syncthreads();
    *(short8*)&As[srow][sch * 8] = av;
    *(short8*)&Ws[srow][sch * 8] = wv;
    __syncthreads();
    if (kt < 63) {
      av = *(const short8*)(ag + (kt + 1) * 32);
      wv = *(const short8*)(wg + (kt + 1) * 32);
    }
    short8 af = *(const short8*)&As[wave * 16 + l15][lq * 8];
#pragma unroll
    for (int fn = 0; fn < 4; ++fn) {
      short8 bf = *(const short8*)&Ws[fn * 16 + l15][lq * 8];
      acc[fn] = MFMA16(af, bf, acc[fn]);
    }
  }
  const int b = bg >> 4, g = bg & 15;
#pragma unroll
  for (int fn = 0; fn < 4; ++fn) {
#pragma unroll
    for (int r = 0; r < 4; ++r) {
      int row = i_base + r0 + wave * 16 + lq * 4 + r;
      int col = g * 64 + fn * 16 + l15;
      out[((size_t)b * 2048 + row) * 1024 + col] = acc[fn][r];
    }
  }
}

// ----------------------------- launcher ------------------------------------
extern "C" void kernel_launch(void* const* d_in, const int* in_sizes, int n_in,
                              void* d_out, int out_size, void* d_ws,
                              size_t ws_size, hipStream_t stream) {
  const float* x = (const float*)d_in[0];
  const float* ctx = (const float*)d_in[1];
  const float* Wq = (const float*)d_in[2];
  const float* Wkv = (const float*)d_in[3];
  const float* Wtalk = (const float*)d_in[4];
  const float* gam = (const float*)d_in[5];
  const float* bet = (const float*)d_in[6];
  float* out = (float*)d_out;

  // persistent region (alive across the whole pipeline)
  u16* ws = (u16*)d_ws;
  u16* qhb = ws;                   // 4 Mi elems  [b][h][n][64]
  u16* khb = ws + 4194304;         // 4 Mi        [b][h][j][64]
  u16* vtb = ws + 8388608;         // 4 Mi        [b][h][d][2048]
  float* lsum = (float*)(ws + 12582912);  // 64 Ki f32
  // scratch region: cast/proj temporaries, later overlaid by E (32 Mi elems)
  u16* scr = ws + 12845056;
  u16* xb = scr;                   // 4 Mi
  u16* cb = scr + 4194304;         // 4 Mi
  u16* wqb = scr + 8388608;        // 1 Mi
  u16* wkvb = scr + 9437184;       // 2 Mi
  u16* vhb = scr + 11534336;       // 4 Mi
  u16* E = scr;                    // 32 Mi elems (64 MB), per-quarter reuse

  hipMemsetAsync(lsum, 0, 65536 * sizeof(float), stream);

  cast_bf16<<<2048, 256, 0, stream>>>(x, xb, 4194304);
  cast_bf16<<<2048, 256, 0, stream>>>(ctx, cb, 4194304);
  cast_bf16<<<512, 256, 0, stream>>>(Wq, wqb, 1048576);
  cast_bf16<<<1024, 256, 0, stream>>>(Wkv, wkvb, 2097152);

  gemm_bt<0><<<dim3(64, 16), 256, 0, stream>>>(xb, wqb, qhb, nullptr);
  gemm_bt<1><<<dim3(64, 32), 256, 0, stream>>>(cb, wkvb, khb, vhb);

  transpose_v<<<dim3(32, 16, 2), 256, 0, stream>>>(vhb, vtb);

  for (int q = 0; q < 4; ++q) {
    int i_base = q * 512;
    qk_exp<<<dim3(8, 32, 32), 256, 0, stream>>>(qhb, khb, E, lsum, i_base);
    talk_ln<<<dim3(4, 512, 2), 256, 0, stream>>>(E, lsum, Wtalk, gam, bet,
                                                 i_base);
    pv_gemm<<<dim3(8, 32), 256, 0, stream>>>(E, vtb, out, i_base);
  }
}